// Round 3
// baseline (1301.616 us; speedup 1.0000x reference)
//
#include <hip/hip_runtime.h>
#include <math.h>

#define NEXP 8
#define TILE 128
#define BK 32
#define DSPLIT 4

typedef __attribute__((ext_vector_type(8))) short short8;
typedef __attribute__((ext_vector_type(4))) float float4v;

__device__ __forceinline__ unsigned short f2bf(float f) {
  union { float f; unsigned u; } v; v.f = f;
  unsigned r = v.u + 0x7FFFu + ((v.u >> 16) & 1u);  // RNE
  return (unsigned short)(r >> 16);
}
__device__ __forceinline__ unsigned pack2(float a, float b) {
  return (unsigned)f2bf(a) | ((unsigned)f2bf(b) << 16);
}

// ---------------- x -> bf16 (row-major, for gathered A-fragment loads) ----------------
__global__ __launch_bounds__(256) void convert_x_kernel(
    const float* __restrict__ x, unsigned short* __restrict__ xb, int n4) {
  int i = blockIdx.x * 256 + threadIdx.x;
  if (i >= n4) return;
  float4 v = ((const float4*)x)[i];
  uint2 o; o.x = pack2(v.x, v.y); o.y = pack2(v.z, v.w);
  ((uint2*)xb)[i] = o;
}

// ---------------- pack fp32 weights -> bf16 MFMA-fragment-linear panels ----------------
// src: [E][R][K] fp32. Panel (e, rt, ks) = 128x32 bf16, laid out as 8 sub-blocks
// (16 rows each) x 64 lanes x 8 bf16: fragment for lane = row (sub*16+l15),
// cols (ks*32 + quad*8 .. +7). One wave's ni-fragment load is 1KB contiguous.
__global__ __launch_bounds__(256) void pack_frag_kernel(
    const float* __restrict__ src, unsigned short* __restrict__ dst, int K) {
  const int ks = blockIdx.x, rt = blockIdx.y, e = blockIdx.z;
  const int n_ks = gridDim.x, n_rt = gridDim.y;
  const size_t R = (size_t)n_rt * TILE;
  const int tid = threadIdx.x;
  unsigned short* dpan = dst + ((size_t)(e * n_rt + rt) * n_ks + ks) * 4096;
#pragma unroll
  for (int rep = 0; rep < 2; ++rep) {
    int idx = rep * 256 + tid;
    int sub = idx >> 6, lane = idx & 63;
    int l15 = lane & 15, quad = lane >> 4;
    const float4* s = (const float4*)(src + ((size_t)e * R + rt * TILE + sub * 16 + l15) * K
                                      + ks * BK + quad * 8);
    float4 v0 = s[0], v1 = s[1];
    uint4 o;
    o.x = pack2(v0.x, v0.y); o.y = pack2(v0.z, v0.w);
    o.z = pack2(v1.x, v1.y); o.w = pack2(v1.z, v1.w);
    *(uint4*)(dpan + (size_t)idx * 8) = o;
  }
}

// ---------------- routing (fp32, selection-exact) ----------------
__global__ __launch_bounds__(256) void routing_kernel(
    const float* __restrict__ x, const float* __restrict__ cw,
    const float* __restrict__ cb, const float* __restrict__ wealth,
    int* __restrict__ plist, int* __restrict__ counts,
    float* __restrict__ w_rt, int T, int H) {
  const int t = blockIdx.x;
  const int tid = threadIdx.x;
  const float* xr = x + (size_t)t * H;
  float acc[NEXP];
#pragma unroll
  for (int e = 0; e < NEXP; ++e) acc[e] = 0.f;
  for (int h = tid; h < H; h += 256) {
    float xv = xr[h];
#pragma unroll
    for (int e = 0; e < NEXP; ++e) acc[e] += xv * cw[e * H + h];
  }
  __shared__ float s[NEXP][256];
#pragma unroll
  for (int e = 0; e < NEXP; ++e) s[e][tid] = acc[e];
  __syncthreads();
  for (int st = 128; st > 0; st >>= 1) {
    if (tid < st) {
#pragma unroll
      for (int e = 0; e < NEXP; ++e) s[e][tid] += s[e][tid + st];
    }
    __syncthreads();
  }
  if (tid == 0) {
    float bids[NEXP];
#pragma unroll
    for (int e = 0; e < NEXP; ++e) {
      float lg = s[e][0] + cb[e];
      float c = 1.f / (1.f + expf(-lg));
      bids[e] = c * wealth[e];
    }
    int i0 = 0;
    for (int e = 1; e < NEXP; ++e) if (bids[e] > bids[i0]) i0 = e;  // ties -> lower idx
    int i1 = (i0 == 0) ? 1 : 0;
    for (int e = 0; e < NEXP; ++e) if (e != i0 && bids[e] > bids[i1]) i1 = e;
    float ex = expf(bids[i1] - bids[i0]);
    float wsum = 1.f + ex;
    w_rt[2 * t]     = 1.f / wsum;
    w_rt[2 * t + 1] = ex / wsum;
    int p0 = atomicAdd(&counts[i0], 1);
    plist[i0 * T + p0] = 2 * t;
    int p1 = atomicAdd(&counts[i1], 1);
    plist[i1 * T + p1] = 2 * t + 1;
  }
}

// ---------------- gate+up fused GEMM: barrier-free, register-direct ----------------
__global__ __launch_bounds__(256, 2) void gateup_kernel(
    const unsigned short* __restrict__ xb, const unsigned short* __restrict__ gwp,
    const unsigned short* __restrict__ uwp, const int* __restrict__ plist,
    const int* __restrict__ counts, unsigned short* __restrict__ act,
    int T, int H, int I) {
  const int e = blockIdx.z;
  const int cnt = counts[e];
  const int row0 = blockIdx.x * TILE;
  if (row0 >= cnt) return;
  const int it = blockIdx.y;
  const int n_it = gridDim.y;
  const int nks = H / BK;

  const int tid = threadIdx.x, lane = tid & 63, wv = tid >> 6;
  const int wm = wv >> 1, wn = wv & 1;
  const int quad = lane >> 4, l15 = lane & 15;

  // A fragment row pointers: lane holds A[m=l15][k=quad*8..+7] of each mi block
  const unsigned short* ap[4];
#pragma unroll
  for (int mi = 0; mi < 4; ++mi) {
    int ri = row0 + wm * 64 + mi * 16 + l15;
    if (ri >= cnt) ri = cnt - 1;
    int tok = plist[e * T + ri] >> 1;
    ap[mi] = xb + (size_t)tok * H + quad * 8;
  }
  // B fragment pointers (fragment-linear panels): 1KB contiguous per (ni,k)
  const unsigned short* gp = gwp + ((((size_t)(e * n_it + it) * nks) * 8 + wn * 4) * 512) + lane * 8;
  const unsigned short* up = uwp + ((((size_t)(e * n_it + it) * nks) * 8 + wn * 4) * 512) + lane * 8;

  float4v accg[4][4], accu[4][4];
#pragma unroll
  for (int a = 0; a < 4; ++a)
#pragma unroll
    for (int b = 0; b < 4; ++b) {
      float4v z = {0.f, 0.f, 0.f, 0.f};
      accg[a][b] = z; accu[a][b] = z;
    }

  for (int k = 0; k < nks; ++k) {
    short8 af[4], bg[4], bu[4];
#pragma unroll
    for (int mi = 0; mi < 4; ++mi) af[mi] = *(const short8*)(ap[mi]);
#pragma unroll
    for (int ni = 0; ni < 4; ++ni) {
      bg[ni] = *(const short8*)(gp + ni * 512);
      bu[ni] = *(const short8*)(up + ni * 512);
    }
#pragma unroll
    for (int mi = 0; mi < 4; ++mi) ap[mi] += BK;
    gp += 4096; up += 4096;
#pragma unroll
    for (int mi = 0; mi < 4; ++mi)
#pragma unroll
      for (int ni = 0; ni < 4; ++ni) {
        accg[mi][ni] = __builtin_amdgcn_mfma_f32_16x16x32_bf16(af[mi], bg[ni], accg[mi][ni], 0, 0, 0);
        accu[mi][ni] = __builtin_amdgcn_mfma_f32_16x16x32_bf16(af[mi], bu[ni], accu[mi][ni], 0, 0, 0);
      }
  }

  // epilogue: C/D layout col=lane&15, row=quad*4+reg
#pragma unroll
  for (int mi = 0; mi < 4; ++mi) {
    int rbase = wm * 64 + mi * 16 + quad * 4;
#pragma unroll
    for (int r = 0; r < 4; ++r) {
      int grow = row0 + rbase + r;
      if (grow < cnt) {
        int p = plist[e * T + grow];
        size_t base = (size_t)p * I + it * TILE + wn * 64 + l15;
#pragma unroll
        for (int ni = 0; ni < 4; ++ni) {
          float g = accg[mi][ni][r];
          float u = accu[mi][ni][r];
          float s = g / (1.f + __expf(-g)) * u;  // silu(g)*u
          act[base + ni * 16] = f2bf(s);
        }
      }
    }
  }
}

// ---------------- down GEMM: barrier-free, register-direct, split-K ----------------
__global__ __launch_bounds__(256, 2) void down_kernel(
    const unsigned short* __restrict__ act, const unsigned short* __restrict__ dwp,
    const int* __restrict__ plist, const int* __restrict__ counts,
    float* __restrict__ part, int T, int H, int I) {
  const int zz = blockIdx.z;
  const int e = zz >> 2, split = zz & 3;
  const int cnt = counts[e];
  const int row0 = blockIdx.x * TILE;
  if (row0 >= cnt) return;
  const int ht = blockIdx.y;
  const int n_ht = gridDim.y;
  const int nks_tot = I / BK;
  const int nks = nks_tot / DSPLIT;
  const int k0 = split * nks;

  const int tid = threadIdx.x, lane = tid & 63, wv = tid >> 6;
  const int wm = wv >> 1, wn = wv & 1;
  const int quad = lane >> 4, l15 = lane & 15;

  const unsigned short* ap[4];
  int prow[4];
#pragma unroll
  for (int mi = 0; mi < 4; ++mi) {
    int ri = row0 + wm * 64 + mi * 16 + l15;
    if (ri >= cnt) ri = cnt - 1;
    int p = plist[e * T + ri];
    prow[mi] = p;
    ap[mi] = act + (size_t)p * I + k0 * BK + quad * 8;
  }
  const unsigned short* bp = dwp + ((((size_t)(e * n_ht + ht) * nks_tot + k0) * 8 + wn * 4) * 512) + lane * 8;

  float4v acc[4][4];
#pragma unroll
  for (int a = 0; a < 4; ++a)
#pragma unroll
    for (int b = 0; b < 4; ++b) { float4v z = {0.f, 0.f, 0.f, 0.f}; acc[a][b] = z; }

  for (int k = 0; k < nks; ++k) {
    short8 af[4], bf[4];
#pragma unroll
    for (int mi = 0; mi < 4; ++mi) af[mi] = *(const short8*)(ap[mi]);
#pragma unroll
    for (int ni = 0; ni < 4; ++ni) bf[ni] = *(const short8*)(bp + ni * 512);
#pragma unroll
    for (int mi = 0; mi < 4; ++mi) ap[mi] += BK;
    bp += 4096;
#pragma unroll
    for (int mi = 0; mi < 4; ++mi)
#pragma unroll
      for (int ni = 0; ni < 4; ++ni)
        acc[mi][ni] = __builtin_amdgcn_mfma_f32_16x16x32_bf16(af[mi], bf[ni], acc[mi][ni], 0, 0, 0);
  }

#pragma unroll
  for (int mi = 0; mi < 4; ++mi) {
    int rbase = wm * 64 + mi * 16 + quad * 4;
#pragma unroll
    for (int r = 0; r < 4; ++r) {
      int grow = row0 + rbase + r;
      if (grow < cnt) {
        int p = plist[e * T + grow];
        size_t base = ((size_t)split * 2 * T + p) * H + ht * TILE + wn * 64 + l15;
#pragma unroll
        for (int ni = 0; ni < 4; ++ni)
          part[base + ni * 16] = acc[mi][ni][r];
      }
    }
  }
}

// ---------------- combine: out = w0*sum_s(pa[s]) + w1*sum_s(pb[s]) ----------------
__global__ __launch_bounds__(256) void combine_kernel(
    const float* __restrict__ part, const float* __restrict__ w_rt,
    float* __restrict__ out, int T, int H) {
  int h4 = H >> 2;
  int n4 = T * h4;
  int i = blockIdx.x * 256 + threadIdx.x;
  if (i >= n4) return;
  int t = i / h4;
  int c = i - t * h4;
  float w0 = w_rt[2 * t], w1 = w_rt[2 * t + 1];
  size_t so = (size_t)2 * T * H / 4;  // split stride in float4 units
  const float4* pa = (const float4*)(part + (size_t)(2 * t) * H);
  const float4* pb = (const float4*)(part + (size_t)(2 * t + 1) * H);
  float ax = 0, ay = 0, az = 0, aw = 0, bx = 0, by = 0, bz = 0, bw = 0;
#pragma unroll
  for (int s = 0; s < DSPLIT; ++s) {
    float4 a = pa[c + s * so], b = pb[c + s * so];
    ax += a.x; ay += a.y; az += a.z; aw += a.w;
    bx += b.x; by += b.y; bz += b.z; bw += b.w;
  }
  float4 o;
  o.x = w0 * ax + w1 * bx;
  o.y = w0 * ay + w1 * by;
  o.z = w0 * az + w1 * bz;
  o.w = w0 * aw + w1 * bw;
  ((float4*)(out + (size_t)t * H))[c] = o;
}

extern "C" void kernel_launch(void* const* d_in, const int* in_sizes, int n_in,
                              void* d_out, int out_size, void* d_ws, size_t ws_size,
                              hipStream_t stream) {
  const float* x      = (const float*)d_in[0];
  const float* cw     = (const float*)d_in[1];
  const float* cb     = (const float*)d_in[2];
  const float* gw     = (const float*)d_in[3];
  const float* uw     = (const float*)d_in[4];
  const float* dw     = (const float*)d_in[5];
  const float* wealth = (const float*)d_in[6];
  float* out = (float*)d_out;

  const int H = in_sizes[1] / NEXP;          // conf_w (E,H)
  const int T = in_sizes[0] / H;             // hidden (B*S,H)
  const int I = in_sizes[3] / (NEXP * H);    // gate_w (E,I,H)

  char* ws = (char*)d_ws;
  size_t off = 0;
  unsigned short* xb  = (unsigned short*)(ws + off); off += (size_t)T * H * 2;
  unsigned short* act = (unsigned short*)(ws + off); off += (size_t)2 * T * I * 2;
  float* part = (float*)(ws + off); off += (size_t)DSPLIT * 2 * T * H * 4;
  unsigned short* gwp = (unsigned short*)(ws + off); off += (size_t)NEXP * I * H * 2;
  unsigned short* uwp = (unsigned short*)(ws + off); off += (size_t)NEXP * I * H * 2;
  unsigned short* dwp = gwp;  // reuse: dw pack launched after gateup completes (same stream)
  int* plist = (int*)(ws + off); off += (size_t)NEXP * T * 4;
  float* w_rt = (float*)(ws + off); off += (size_t)T * 2 * 4;
  int* counts = (int*)(ws + off); off += NEXP * 4;

  hipMemsetAsync(counts, 0, NEXP * sizeof(int), stream);

  int n4 = (T * H) / 4;
  convert_x_kernel<<<(n4 + 255) / 256, 256, 0, stream>>>(x, xb, n4);
  routing_kernel<<<T, 256, 0, stream>>>(x, cw, cb, wealth, plist, counts, w_rt, T, H);

  dim3 gp(H / BK, I / TILE, NEXP);
  pack_frag_kernel<<<gp, 256, 0, stream>>>(gw, gwp, H);
  pack_frag_kernel<<<gp, 256, 0, stream>>>(uw, uwp, H);

  int ttiles = (T + TILE - 1) / TILE;
  dim3 g1(ttiles, I / TILE, NEXP);
  gateup_kernel<<<g1, 256, 0, stream>>>(xb, gwp, uwp, plist, counts, act, T, H, I);

  dim3 gpd(I / BK, H / TILE, NEXP);
  pack_frag_kernel<<<gpd, 256, 0, stream>>>(dw, dwp, I);

  dim3 g2(ttiles, H / TILE, NEXP * DSPLIT);  // z = expert*DSPLIT + ksplit
  down_kernel<<<g2, 256, 0, stream>>>(act, dwp, plist, counts, part, T, H, I);

  combine_kernel<<<(n4 + 255) / 256, 256, 0, stream>>>(part, w_rt, out, T, H);
}